// Round 1
// baseline (782.560 us; speedup 1.0000x reference)
//
#include <hip/hip_runtime.h>

typedef unsigned short u16;
typedef unsigned int   u32;
typedef __attribute__((ext_vector_type(4))) float  f32x4;
typedef __attribute__((ext_vector_type(8))) __bf16 bf16x8;

#define EMBED 2048
#define NH    16
#define NKV   4
#define HD    128
#define TT    2048
#define BB    2
#define MROWS (BB*TT)
#define QSCALE 0.08838834764831845f

static __device__ __forceinline__ u16 f2b(float f){
  union { float f; u32 u; } v; v.f = f;
  u32 u = v.u;
  u32 r = u + 0x7FFFu + ((u >> 16) & 1u);   // RNE
  return (u16)(r >> 16);
}

// ---------------- fp32 -> bf16 convert (x) ----------------
__global__ __launch_bounds__(256) void cvt_f32_bf16(const float* __restrict__ in,
                                                    u16* __restrict__ out, int n4){
  int i = blockIdx.x * 256 + threadIdx.x;
  if (i >= n4) return;
  float4 v = ((const float4*)in)[i];
  uint2 o;
  o.x = (u32)f2b(v.x) | ((u32)f2b(v.y) << 16);
  o.y = (u32)f2b(v.z) | ((u32)f2b(v.w) << 16);
  ((uint2*)out)[i] = o;
}

// ---------------- fp32 [R][C] -> bf16 [C][R] (weights to B^T form) ----------------
__global__ __launch_bounds__(256) void trans_w(const float* __restrict__ in,
                                               u16* __restrict__ out, int R, int C){
  __shared__ u16 tile[32][33];
  int c0 = blockIdx.x * 32, r0 = blockIdx.y * 32;
  int tx = threadIdx.x & 31, ty = threadIdx.x >> 5;   // 32 x 8
  #pragma unroll
  for (int j = 0; j < 32; j += 8)
    tile[ty + j][tx] = f2b(in[(size_t)(r0 + ty + j) * C + c0 + tx]);
  __syncthreads();
  #pragma unroll
  for (int j = 0; j < 32; j += 8)
    out[(size_t)(c0 + ty + j) * R + r0 + tx] = tile[tx][ty + j];
}

// ---------------- bf16 [BH][T][D] -> [BH][D][T]  (V for PV fragment reads) ----------------
__global__ __launch_bounds__(256) void trans_v(const u16* __restrict__ in,
                                               u16* __restrict__ out){
  __shared__ u16 tile[32][33];
  int d0 = (blockIdx.x & 3) * 32;            // D/32 = 4
  int t0 = ((blockIdx.x >> 2) & 63) * 32;    // T/32 = 64
  int bh = blockIdx.x >> 8;                  // B*NKV = 8
  const u16* ip = in  + (size_t)bh * TT * HD;
  u16*       op = out + (size_t)bh * TT * HD;
  int tx = threadIdx.x & 31, ty = threadIdx.x >> 5;
  #pragma unroll
  for (int j = 0; j < 32; j += 8)
    tile[ty + j][tx] = ip[(size_t)(t0 + ty + j) * HD + d0 + tx];
  __syncthreads();
  #pragma unroll
  for (int j = 0; j < 32; j += 8)
    op[(size_t)(d0 + ty + j) * TT + t0 + tx] = tile[tx][ty + j];
}

// ---------------- bf16 GEMM: C[M,N] = A[M,K] * Bt[N,K]^T ----------------
// EPI 0: fp32 [M][N] out.   EPI 1: bf16 out[((b*Hh + col/128)*T + t)*128 + col%128] * scale
template<int EPI>
__global__ __launch_bounds__(256)
void gemm_bt(const u16* __restrict__ A, const u16* __restrict__ Bt,
             void* __restrict__ outp, int N, int K, int Hh, float scale){
  __shared__ __align__(16) u16 As[2][128*32];
  __shared__ __align__(16) u16 Bs[2][128*32];
  int tid  = threadIdx.x;
  int lane = tid & 63, w = tid >> 6;
  int nwg = gridDim.x;
  int bid = blockIdx.x;
  bid = (bid & 7) * (nwg >> 3) + (bid >> 3);      // XCD swizzle (nwg % 8 == 0 always here)
  int nbn  = N >> 7;
  int brow = (bid / nbn) * 128;
  int bcol = (bid % nbn) * 128;

  auto stage = [&](int buf, int kt){
    #pragma unroll
    for (int j = 0; j < 2; ++j){
      int boff  = w * 2048 + j * 1024;            // byte offset into 8KB tile (wave-uniform)
      int chunk = (boff >> 4) + lane;             // this lane's 16B chunk id
      int row   = chunk >> 2;                     // 4 chunks per 64B row
      int cko   = chunk & 3;
      const u16* ga = A  + (size_t)(brow + row) * K + kt + cko * 8;
      const u16* gb = Bt + (size_t)(bcol + row) * K + kt + cko * 8;
      __builtin_amdgcn_global_load_lds((__attribute__((address_space(1))) void*)(void*)ga,
          (__attribute__((address_space(3))) void*)(void*)(&As[buf][boff >> 1]), 16, 0, 0);
      __builtin_amdgcn_global_load_lds((__attribute__((address_space(1))) void*)(void*)gb,
          (__attribute__((address_space(3))) void*)(void*)(&Bs[buf][boff >> 1]), 16, 0, 0);
    }
  };

  int lr = lane & 15, lg = lane >> 4, lk = lg * 8;
  int wr = (w >> 1) * 64, wc = (w & 1) * 64;

  f32x4 acc[4][4];
  #pragma unroll
  for (int m = 0; m < 4; ++m)
    #pragma unroll
    for (int n = 0; n < 4; ++n)
      #pragma unroll
      for (int r = 0; r < 4; ++r) acc[m][n][r] = 0.f;

  int NT = K >> 5;
  stage(0, 0);
  asm volatile("s_waitcnt vmcnt(0)" ::: "memory");
  __syncthreads();
  int cur = 0;
  for (int t = 0; t < NT; ++t){
    if (t + 1 < NT) stage(cur ^ 1, (t + 1) * 32);
    const u16* as = As[cur];
    const u16* bs = Bs[cur];
    bf16x8 af[4], bfv[4];
    #pragma unroll
    for (int m = 0; m < 4; ++m) af[m]  = *(const bf16x8*)(as + (wr + m*16 + lr)*32 + lk);
    #pragma unroll
    for (int n = 0; n < 4; ++n) bfv[n] = *(const bf16x8*)(bs + (wc + n*16 + lr)*32 + lk);
    #pragma unroll
    for (int m = 0; m < 4; ++m)
      #pragma unroll
      for (int n = 0; n < 4; ++n)
        acc[m][n] = __builtin_amdgcn_mfma_f32_16x16x32_bf16(af[m], bfv[n], acc[m][n], 0, 0, 0);
    asm volatile("s_waitcnt vmcnt(0)" ::: "memory");
    __syncthreads();
    cur ^= 1;
  }

  if (EPI == 0){
    float* o = (float*)outp;
    #pragma unroll
    for (int m = 0; m < 4; ++m)
      #pragma unroll
      for (int r = 0; r < 4; ++r){
        int rowg = brow + wr + m*16 + lg*4 + r;
        float* orow = o + (size_t)rowg * N + bcol + wc + lr;
        #pragma unroll
        for (int n = 0; n < 4; ++n) orow[n*16] = acc[m][n][r];
      }
  } else {
    u16* o = (u16*)outp;
    #pragma unroll
    for (int m = 0; m < 4; ++m)
      #pragma unroll
      for (int r = 0; r < 4; ++r){
        int rowg = brow + wr + m*16 + lg*4 + r;
        int b = rowg >> 11;                 // M = 2*2048
        int t = rowg & (TT - 1);
        #pragma unroll
        for (int n = 0; n < 4; ++n){
          int colg = bcol + wc + n*16 + lr;
          int h = colg >> 7, d = colg & 127;
          o[(((size_t)b * Hh + h) * TT + t) * HD + d] = f2b(acc[m][n][r] * scale);
        }
      }
  }
}

// ---------------- flash attention: q[B,NH,T,D] (pre-scaled), k[B,NKV,T,D], vt[B,NKV,D,T] -> ob[B,T,NH,D] bf16
__global__ __launch_bounds__(256)
void attn_kernel(const u16* __restrict__ qb, const u16* __restrict__ kb,
                 const u16* __restrict__ vtb, u16* __restrict__ ob){
  __shared__ __align__(16) u16 pl[4][16 * 80];   // per-wave P scratch, stride 80 (pad vs conflicts)
  int tid = threadIdx.x, lane = tid & 63, w = tid >> 6;
  int bid = blockIdx.x;
  int qt  = bid & 31;            // T/64
  int h   = (bid >> 5) & 15;
  int b   = bid >> 9;
  int hkv = h >> 2;              // GROUP = 4, consecutive repeat
  int lr = lane & 15, lg = lane >> 4, lk = lg * 8;

  const u16* qbase = qb  + ((size_t)b * NH  + h  ) * TT * HD;
  const u16* kbase = kb  + ((size_t)b * NKV + hkv) * TT * HD;
  const u16* vbase = vtb + ((size_t)b * NKV + hkv) * HD * TT;

  int q0 = qt * 64 + w * 16;
  bf16x8 aq[4];
  #pragma unroll
  for (int s = 0; s < 4; ++s)
    aq[s] = *(const bf16x8*)(qbase + (size_t)(q0 + lr) * HD + s*32 + lk);

  f32x4 o_acc[8];
  #pragma unroll
  for (int dt = 0; dt < 8; ++dt)
    #pragma unroll
    for (int r = 0; r < 4; ++r) o_acc[dt][r] = 0.f;
  float mrow[4], lrow[4];
  #pragma unroll
  for (int r = 0; r < 4; ++r){ mrow[r] = -1e30f; lrow[r] = 0.f; }

  u16* plw = pl[w];

  for (int kt = 0; kt <= qt; ++kt){
    // ---- scores = Q K^T (16 x 64), direct-global K fragments (L2-resident) ----
    f32x4 sc[4];
    #pragma unroll
    for (int c = 0; c < 4; ++c)
      #pragma unroll
      for (int r = 0; r < 4; ++r) sc[c][r] = 0.f;
    #pragma unroll
    for (int c = 0; c < 4; ++c){
      const u16* kp = kbase + (size_t)(kt*64 + c*16 + lr) * HD + lk;
      #pragma unroll
      for (int s = 0; s < 4; ++s){
        bf16x8 kf = *(const bf16x8*)(kp + s*32);
        sc[c] = __builtin_amdgcn_mfma_f32_16x16x32_bf16(aq[s], kf, sc[c], 0, 0, 0);
      }
    }
    if (kt == qt){
      #pragma unroll
      for (int c = 0; c < 4; ++c){
        int kvg = kt*64 + c*16 + lr;
        #pragma unroll
        for (int r = 0; r < 4; ++r){
          int qg = qt*64 + w*16 + lg*4 + r;   // C-layout row
          if (kvg > qg) sc[c][r] = -1e30f;
        }
      }
    }
    // ---- online softmax (per C-layout row r; reduce across the 16-lane col group) ----
    #pragma unroll
    for (int r = 0; r < 4; ++r){
      float tm = fmaxf(fmaxf(sc[0][r], sc[1][r]), fmaxf(sc[2][r], sc[3][r]));
      tm = fmaxf(tm, __shfl_xor(tm, 1));
      tm = fmaxf(tm, __shfl_xor(tm, 2));
      tm = fmaxf(tm, __shfl_xor(tm, 4));
      tm = fmaxf(tm, __shfl_xor(tm, 8));
      float mnew  = fmaxf(mrow[r], tm);
      float alpha = __expf(mrow[r] - mnew);
      mrow[r] = mnew;
      float rs = 0.f;
      #pragma unroll
      for (int c = 0; c < 4; ++c){
        float p = __expf(sc[c][r] - mnew);
        rs += p;
        plw[(lg*4 + r)*80 + c*16 + lr] = f2b(p);
      }
      rs += __shfl_xor(rs, 1); rs += __shfl_xor(rs, 2);
      rs += __shfl_xor(rs, 4); rs += __shfl_xor(rs, 8);
      lrow[r] = lrow[r] * alpha + rs;
      #pragma unroll
      for (int dt = 0; dt < 8; ++dt) o_acc[dt][r] *= alpha;
    }
    asm volatile("s_waitcnt lgkmcnt(0)" ::: "memory");
    // ---- O += P V, P re-read in A-layout, V fragments direct-global from [D][T] ----
    bf16x8 pa[2];
    #pragma unroll
    for (int kk = 0; kk < 2; ++kk)
      pa[kk] = *(const bf16x8*)(plw + lr*80 + kk*32 + lk);
    #pragma unroll
    for (int dt = 0; dt < 8; ++dt){
      const u16* vp = vbase + (size_t)(dt*16 + lr) * TT + kt*64 + lk;
      #pragma unroll
      for (int kk = 0; kk < 2; ++kk){
        bf16x8 vf = *(const bf16x8*)(vp + kk*32);
        o_acc[dt] = __builtin_amdgcn_mfma_f32_16x16x32_bf16(pa[kk], vf, o_acc[dt], 0, 0, 0);
      }
    }
  }
  // ---- epilogue: ob[b][t][h*128+d] = O / l ----
  #pragma unroll
  for (int r = 0; r < 4; ++r){
    float inv = 1.0f / lrow[r];
    int t = qt*64 + w*16 + lg*4 + r;
    size_t base = ((size_t)b * TT + t) * EMBED + h * HD;
    #pragma unroll
    for (int dt = 0; dt < 8; ++dt)
      ob[base + dt*16 + lr] = f2b(o_acc[dt][r] * inv);
  }
}

extern "C" void kernel_launch(void* const* d_in, const int* in_sizes, int n_in,
                              void* d_out, int out_size, void* d_ws, size_t ws_size,
                              hipStream_t stream){
  const float* x  = (const float*)d_in[0];
  const float* Wq = (const float*)d_in[1];
  const float* Wk = (const float*)d_in[2];
  const float* Wv = (const float*)d_in[3];
  const float* Wo = (const float*)d_in[4];

  char* ws = (char*)d_ws;
  size_t off = 0;
  auto alloc = [&](size_t bytes){ void* p = ws + off; off += (bytes + 255) & ~(size_t)255; return p; };
  u16* xb  = (u16*)alloc((size_t)MROWS * EMBED * 2);
  u16* Wqt = (u16*)alloc((size_t)EMBED * EMBED * 2);
  u16* Wkt = (u16*)alloc((size_t)512 * EMBED * 2);
  u16* Wvt = (u16*)alloc((size_t)512 * EMBED * 2);
  u16* Wot = (u16*)alloc((size_t)EMBED * EMBED * 2);
  u16* qb  = (u16*)alloc((size_t)BB * NH  * TT * HD * 2);
  u16* kb  = (u16*)alloc((size_t)BB * NKV * TT * HD * 2);
  u16* vb  = (u16*)alloc((size_t)BB * NKV * TT * HD * 2);
  u16* vtb = (u16*)alloc((size_t)BB * NKV * TT * HD * 2);
  u16* ob  = (u16*)alloc((size_t)MROWS * EMBED * 2);

  cvt_f32_bf16<<<(MROWS*EMBED/4 + 255)/256, 256, 0, stream>>>(x, xb, MROWS*EMBED/4);
  trans_w<<<dim3(EMBED/32, EMBED/32), 256, 0, stream>>>(Wq, Wqt, EMBED, EMBED);
  trans_w<<<dim3(512/32,   EMBED/32), 256, 0, stream>>>(Wk, Wkt, EMBED, 512);
  trans_w<<<dim3(512/32,   EMBED/32), 256, 0, stream>>>(Wv, Wvt, EMBED, 512);
  trans_w<<<dim3(EMBED/32, EMBED/32), 256, 0, stream>>>(Wo, Wot, EMBED, EMBED);

  gemm_bt<1><<<(MROWS/128)*(EMBED/128), 256, 0, stream>>>(xb, Wqt, qb, EMBED, EMBED, NH,  QSCALE);
  gemm_bt<1><<<(MROWS/128)*(512/128),   256, 0, stream>>>(xb, Wkt, kb, 512,   EMBED, NKV, 1.0f);
  gemm_bt<1><<<(MROWS/128)*(512/128),   256, 0, stream>>>(xb, Wvt, vb, 512,   EMBED, NKV, 1.0f);
  trans_v<<<4*64*BB*NKV, 256, 0, stream>>>(vb, vtb);

  attn_kernel<<<BB*NH*(TT/64), 256, 0, stream>>>(qb, kb, vtb, ob);

  gemm_bt<0><<<(MROWS/128)*(EMBED/128), 256, 0, stream>>>(ob, Wot, d_out, EMBED, EMBED, 0, 1.0f);
}

// Round 2
// 387.008 us; speedup vs baseline: 2.0221x; 2.0221x over previous
//
#include <hip/hip_runtime.h>

typedef unsigned short u16;
typedef unsigned int   u32;
typedef __attribute__((ext_vector_type(4))) float  f32x4;
typedef __attribute__((ext_vector_type(8))) __bf16 bf16x8;

#define EMBED 2048
#define NH    16
#define NKV   4
#define HD    128
#define TT    2048
#define BB    2
#define MROWS (BB*TT)
#define QSCALE 0.08838834764831845f

static __device__ __forceinline__ u16 f2b(float f){
  union { float f; u32 u; } v; v.f = f;
  u32 u = v.u;
  u32 r = u + 0x7FFFu + ((u >> 16) & 1u);   // RNE
  return (u16)(r >> 16);
}

// ---------------- fp32 -> bf16 convert (x) ----------------
__global__ __launch_bounds__(256) void cvt_f32_bf16(const float* __restrict__ in,
                                                    u16* __restrict__ out, int n4){
  int i = blockIdx.x * 256 + threadIdx.x;
  if (i >= n4) return;
  float4 v = ((const float4*)in)[i];
  uint2 o;
  o.x = (u32)f2b(v.x) | ((u32)f2b(v.y) << 16);
  o.y = (u32)f2b(v.z) | ((u32)f2b(v.w) << 16);
  ((uint2*)out)[i] = o;
}

// ---------------- fp32 [R][C] -> bf16 [C][R] (weights to B^T form) ----------------
__global__ __launch_bounds__(256) void trans_w(const float* __restrict__ in,
                                               u16* __restrict__ out, int R, int C){
  __shared__ u16 tile[32][33];
  int c0 = blockIdx.x * 32, r0 = blockIdx.y * 32;
  int tx = threadIdx.x & 31, ty = threadIdx.x >> 5;   // 32 x 8
  #pragma unroll
  for (int j = 0; j < 32; j += 8)
    tile[ty + j][tx] = f2b(in[(size_t)(r0 + ty + j) * C + c0 + tx]);
  __syncthreads();
  #pragma unroll
  for (int j = 0; j < 32; j += 8)
    out[(size_t)(c0 + ty + j) * R + r0 + tx] = tile[tx][ty + j];
}

// ---------------- bf16 [BH][T][D] -> [BH][D][T]  (V for PV fragment reads) ----------------
__global__ __launch_bounds__(256) void trans_v(const u16* __restrict__ in,
                                               u16* __restrict__ out){
  __shared__ u16 tile[32][33];
  int d0 = (blockIdx.x & 3) * 32;            // D/32 = 4
  int t0 = ((blockIdx.x >> 2) & 63) * 32;    // T/32 = 64
  int bh = blockIdx.x >> 8;                  // B*NKV = 8
  const u16* ip = in  + (size_t)bh * TT * HD;
  u16*       op = out + (size_t)bh * TT * HD;
  int tx = threadIdx.x & 31, ty = threadIdx.x >> 5;
  #pragma unroll
  for (int j = 0; j < 32; j += 8)
    tile[ty + j][tx] = ip[(size_t)(t0 + ty + j) * HD + d0 + tx];
  __syncthreads();
  #pragma unroll
  for (int j = 0; j < 32; j += 8)
    op[(size_t)(d0 + ty + j) * TT + t0 + tx] = tile[tx][ty + j];
}

// ---------------- bf16 GEMM: C[M,N] = A[M,K] * Bt[N,K]^T ----------------
// EPI 0: fp32 [M][N] out.   EPI 1: bf16 out[((b*Hh + col/128)*T + t)*128 + col%128] * scale
template<int EPI>
__global__ __launch_bounds__(256)
void gemm_bt(const u16* __restrict__ A, const u16* __restrict__ Bt,
             void* __restrict__ outp, int N, int K, int Hh, float scale){
  __shared__ __align__(16) u16 As[2][128*32];
  __shared__ __align__(16) u16 Bs[2][128*32];
  int tid  = threadIdx.x;
  int lane = tid & 63, w = tid >> 6;
  int nwg = gridDim.x;
  int bid = blockIdx.x;
  bid = (bid & 7) * (nwg >> 3) + (bid >> 3);      // XCD swizzle (nwg % 8 == 0 always here)
  int nbn  = N >> 7;
  int brow = (bid / nbn) * 128;
  int bcol = (bid % nbn) * 128;

  auto stage = [&](int buf, int kt){
    #pragma unroll
    for (int j = 0; j < 2; ++j){
      int boff  = w * 2048 + j * 1024;            // byte offset into 8KB tile (wave-uniform)
      int chunk = (boff >> 4) + lane;             // this lane's 16B chunk id
      int row   = chunk >> 2;                     // 4 chunks per 64B row
      int cko   = chunk & 3;
      const u16* ga = A  + (size_t)(brow + row) * K + kt + cko * 8;
      const u16* gb = Bt + (size_t)(bcol + row) * K + kt + cko * 8;
      __builtin_amdgcn_global_load_lds((__attribute__((address_space(1))) void*)(void*)ga,
          (__attribute__((address_space(3))) void*)(void*)(&As[buf][boff >> 1]), 16, 0, 0);
      __builtin_amdgcn_global_load_lds((__attribute__((address_space(1))) void*)(void*)gb,
          (__attribute__((address_space(3))) void*)(void*)(&Bs[buf][boff >> 1]), 16, 0, 0);
    }
  };

  int lr = lane & 15, lg = lane >> 4, lk = lg * 8;
  int wr = (w >> 1) * 64, wc = (w & 1) * 64;

  f32x4 acc[4][4];
  #pragma unroll
  for (int m = 0; m < 4; ++m)
    #pragma unroll
    for (int n = 0; n < 4; ++n)
      #pragma unroll
      for (int r = 0; r < 4; ++r) acc[m][n][r] = 0.f;

  int NT = K >> 5;
  stage(0, 0);
  asm volatile("s_waitcnt vmcnt(0)" ::: "memory");
  __syncthreads();
  int cur = 0;
  for (int t = 0; t < NT; ++t){
    if (t + 1 < NT) stage(cur ^ 1, (t + 1) * 32);
    const u16* as = As[cur];
    const u16* bs = Bs[cur];
    bf16x8 af[4], bfv[4];
    #pragma unroll
    for (int m = 0; m < 4; ++m) af[m]  = *(const bf16x8*)(as + (wr + m*16 + lr)*32 + lk);
    #pragma unroll
    for (int n = 0; n < 4; ++n) bfv[n] = *(const bf16x8*)(bs + (wc + n*16 + lr)*32 + lk);
    #pragma unroll
    for (int m = 0; m < 4; ++m)
      #pragma unroll
      for (int n = 0; n < 4; ++n)
        acc[m][n] = __builtin_amdgcn_mfma_f32_16x16x32_bf16(af[m], bfv[n], acc[m][n], 0, 0, 0);
    asm volatile("s_waitcnt vmcnt(0)" ::: "memory");
    __syncthreads();
    cur ^= 1;
  }

  if (EPI == 0){
    float* o = (float*)outp;
    #pragma unroll
    for (int m = 0; m < 4; ++m)
      #pragma unroll
      for (int r = 0; r < 4; ++r){
        int rowg = brow + wr + m*16 + lg*4 + r;
        float* orow = o + (size_t)rowg * N + bcol + wc + lr;
        #pragma unroll
        for (int n = 0; n < 4; ++n) orow[n*16] = acc[m][n][r];
      }
  } else {
    u16* o = (u16*)outp;
    #pragma unroll
    for (int m = 0; m < 4; ++m)
      #pragma unroll
      for (int r = 0; r < 4; ++r){
        int rowg = brow + wr + m*16 + lg*4 + r;
        int b = rowg >> 11;                 // M = 2*2048
        int t = rowg & (TT - 1);
        #pragma unroll
        for (int n = 0; n < 4; ++n){
          int colg = bcol + wc + n*16 + lr;
          int h = colg >> 7, d = colg & 127;
          o[(((size_t)b * Hh + h) * TT + t) * HD + d] = f2b(acc[m][n][r] * scale);
        }
      }
  }
}

// ---------------- flash attention v2: LDS-staged K/V (XOR-swizzled), paired q-tiles ----------------
// q[B,NH,T,D] (pre-scaled), k[B,NKV,T,D], vt[B,NKV,D,T] -> ob[B,T,NH,D] bf16
// Block: 4 waves x 16 q-rows = 64-row q-tile; each block does q-tiles {pair, 31-pair} (33 kv-steps, balanced).
__global__ __launch_bounds__(256)
void attn_kernel(const u16* __restrict__ qb, const u16* __restrict__ kb,
                 const u16* __restrict__ vtb, u16* __restrict__ ob){
  __shared__ __align__(16) u16 Ks[2][64*128];   // [kv 64][d 128], chunk-swizzled
  __shared__ __align__(16) u16 Vs[2][128*64];   // [d 128][kv 64], chunk-swizzled
  __shared__ __align__(16) u16 pl[4][16*88];    // per-wave P scratch, stride 88 (2-way max)
  int tid = threadIdx.x, lane = tid & 63, w = tid >> 6;
  int nwg = gridDim.x;                          // 512
  int bid = blockIdx.x;
  bid = (bid & 7) * (nwg >> 3) + (bid >> 3);    // chunked XCD swizzle: one (b,hkv) group per XCD
  int pair = bid & 15;
  int h    = (bid >> 4) & 15;
  int b    = bid >> 8;
  int hkv  = h >> 2;                            // GROUP = 4, consecutive repeat
  int lr = lane & 15, lg = lane >> 4, lk = lg * 8;
  int sw = (lr & 7) << 3;                       // read-side XOR (elements)

  const u16* qbase = qb  + ((size_t)b * NH  + h  ) * TT * HD;
  const u16* kbase = kb  + ((size_t)b * NKV + hkv) * TT * HD;
  const u16* vbase = vtb + ((size_t)b * NKV + hkv) * HD * TT;

  // stage kv-tile kt into buffer buf: linear LDS dest, inverse-swizzled global source chunks
  auto stage = [&](int buf, int kt){
    #pragma unroll
    for (int i = 0; i < 4; ++i){
      int c  = i * 256 + tid;                   // 16B-chunk id (per-lane)
      int ub = (i * 256 + w * 64) * 8;          // wave-uniform LDS elem base
      int kr = c >> 4, kc = (c & 15) ^ (kr & 7);        // K: 16 chunks per 256B row
      const u16* gk = kbase + (size_t)(kt * 64 + kr) * HD + kc * 8;
      __builtin_amdgcn_global_load_lds((__attribute__((address_space(1))) void*)(void*)gk,
          (__attribute__((address_space(3))) void*)(void*)(&Ks[buf][ub]), 16, 0, 0);
      int vr = c >> 3, vc = (c & 7) ^ (vr & 7);         // V: 8 chunks per 128B row
      const u16* gv = vbase + (size_t)vr * TT + kt * 64 + vc * 8;
      __builtin_amdgcn_global_load_lds((__attribute__((address_space(1))) void*)(void*)gv,
          (__attribute__((address_space(3))) void*)(void*)(&Vs[buf][ub]), 16, 0, 0);
    }
  };

  __bf16* plw = (__bf16*)pl[w];

  for (int half = 0; half < 2; ++half){
    int qt = half ? (31 - pair) : pair;
    int q0 = qt * 64 + w * 16;

    bf16x8 aq[4];
    #pragma unroll
    for (int s = 0; s < 4; ++s)
      aq[s] = *(const bf16x8*)(qbase + (size_t)(q0 + lr) * HD + s*32 + lk);

    f32x4 o_acc[8];
    #pragma unroll
    for (int dt = 0; dt < 8; ++dt)
      #pragma unroll
      for (int r = 0; r < 4; ++r) o_acc[dt][r] = 0.f;
    float mrow[4], lrow[4];
    #pragma unroll
    for (int r = 0; r < 4; ++r){ mrow[r] = -1e30f; lrow[r] = 0.f; }

    stage(0, 0);
    asm volatile("s_waitcnt vmcnt(0)" ::: "memory");
    __syncthreads();
    int cur = 0;
    for (int kt = 0; kt <= qt; ++kt){
      if (kt < qt) stage(cur ^ 1, kt + 1);
      // ---- scores = Q K^T (16 x 64) from swizzled LDS ----
      const u16* ks = Ks[cur];
      f32x4 sc[4];
      #pragma unroll
      for (int c = 0; c < 4; ++c)
        #pragma unroll
        for (int r = 0; r < 4; ++r) sc[c][r] = 0.f;
      #pragma unroll
      for (int c = 0; c < 4; ++c){
        const u16* kp = ks + (c*16 + lr) * 128;
        #pragma unroll
        for (int s = 0; s < 4; ++s){
          bf16x8 kf = *(const bf16x8*)(kp + (((s*32) + lk) ^ sw));
          sc[c] = __builtin_amdgcn_mfma_f32_16x16x32_bf16(aq[s], kf, sc[c], 0, 0, 0);
        }
      }
      if (kt == qt){
        #pragma unroll
        for (int c = 0; c < 4; ++c){
          int kvg = kt*64 + c*16 + lr;
          #pragma unroll
          for (int r = 0; r < 4; ++r){
            int qg = q0 + lg*4 + r;             // C-layout row
            if (kvg > qg) sc[c][r] = -1e30f;
          }
        }
      }
      // ---- online softmax (per C-layout row r; reduce across the 16-lane col group) ----
      #pragma unroll
      for (int r = 0; r < 4; ++r){
        float tm = fmaxf(fmaxf(sc[0][r], sc[1][r]), fmaxf(sc[2][r], sc[3][r]));
        tm = fmaxf(tm, __shfl_xor(tm, 1));
        tm = fmaxf(tm, __shfl_xor(tm, 2));
        tm = fmaxf(tm, __shfl_xor(tm, 4));
        tm = fmaxf(tm, __shfl_xor(tm, 8));
        float mnew  = fmaxf(mrow[r], tm);
        float alpha = __expf(mrow[r] - mnew);
        mrow[r] = mnew;
        float rs = 0.f;
        #pragma unroll
        for (int c = 0; c < 4; ++c){
          float p = __expf(sc[c][r] - mnew);
          rs += p;
          plw[(lg*4 + r)*88 + c*16 + lr] = (__bf16)p;
        }
        rs += __shfl_xor(rs, 1); rs += __shfl_xor(rs, 2);
        rs += __shfl_xor(rs, 4); rs += __shfl_xor(rs, 8);
        lrow[r] = lrow[r] * alpha + rs;
        #pragma unroll
        for (int dt = 0; dt < 8; ++dt) o_acc[dt][r] *= alpha;
      }
      asm volatile("s_waitcnt lgkmcnt(0)" ::: "memory");
      // ---- O += P V from swizzled LDS ----
      bf16x8 pa[2];
      #pragma unroll
      for (int kk = 0; kk < 2; ++kk)
        pa[kk] = *(const bf16x8*)((const u16*)plw + lr*88 + kk*32 + lk);
      const u16* vs = Vs[cur];
      #pragma unroll
      for (int dt = 0; dt < 8; ++dt){
        const u16* vp = vs + (dt*16 + lr) * 64;
        #pragma unroll
        for (int kk = 0; kk < 2; ++kk){
          bf16x8 vf = *(const bf16x8*)(vp + (((kk*32) + lk) ^ sw));
          o_acc[dt] = __builtin_amdgcn_mfma_f32_16x16x32_bf16(pa[kk], vf, o_acc[dt], 0, 0, 0);
        }
      }
      asm volatile("s_waitcnt vmcnt(0)" ::: "memory");
      __syncthreads();
      cur ^= 1;
    }
    // ---- epilogue: ob[b][t][h*128+d] = O / l ----
    #pragma unroll
    for (int r = 0; r < 4; ++r){
      float inv = 1.0f / lrow[r];
      int t = q0 + lg*4 + r;
      size_t base = ((size_t)b * TT + t) * EMBED + h * HD;
      #pragma unroll
      for (int dt = 0; dt < 8; ++dt)
        ob[base + dt*16 + lr] = f2b(o_acc[dt][r] * inv);
    }
  }
}

extern "C" void kernel_launch(void* const* d_in, const int* in_sizes, int n_in,
                              void* d_out, int out_size, void* d_ws, size_t ws_size,
                              hipStream_t stream){
  const float* x  = (const float*)d_in[0];
  const float* Wq = (const float*)d_in[1];
  const float* Wk = (const float*)d_in[2];
  const float* Wv = (const float*)d_in[3];
  const float* Wo = (const float*)d_in[4];

  char* ws = (char*)d_ws;
  size_t off = 0;
  auto alloc = [&](size_t bytes){ void* p = ws + off; off += (bytes + 255) & ~(size_t)255; return p; };
  u16* xb  = (u16*)alloc((size_t)MROWS * EMBED * 2);
  u16* Wqt = (u16*)alloc((size_t)EMBED * EMBED * 2);
  u16* Wkt = (u16*)alloc((size_t)512 * EMBED * 2);
  u16* Wvt = (u16*)alloc((size_t)512 * EMBED * 2);
  u16* Wot = (u16*)alloc((size_t)EMBED * EMBED * 2);
  u16* qb  = (u16*)alloc((size_t)BB * NH  * TT * HD * 2);
  u16* kb  = (u16*)alloc((size_t)BB * NKV * TT * HD * 2);
  u16* vb  = (u16*)alloc((size_t)BB * NKV * TT * HD * 2);
  u16* vtb = (u16*)alloc((size_t)BB * NKV * TT * HD * 2);
  u16* ob  = (u16*)alloc((size_t)MROWS * EMBED * 2);

  cvt_f32_bf16<<<(MROWS*EMBED/4 + 255)/256, 256, 0, stream>>>(x, xb, MROWS*EMBED/4);
  trans_w<<<dim3(EMBED/32, EMBED/32), 256, 0, stream>>>(Wq, Wqt, EMBED, EMBED);
  trans_w<<<dim3(512/32,   EMBED/32), 256, 0, stream>>>(Wk, Wkt, EMBED, 512);
  trans_w<<<dim3(512/32,   EMBED/32), 256, 0, stream>>>(Wv, Wvt, EMBED, 512);
  trans_w<<<dim3(EMBED/32, EMBED/32), 256, 0, stream>>>(Wo, Wot, EMBED, EMBED);

  gemm_bt<1><<<(MROWS/128)*(EMBED/128), 256, 0, stream>>>(xb, Wqt, qb, EMBED, EMBED, NH,  QSCALE);
  gemm_bt<1><<<(MROWS/128)*(512/128),   256, 0, stream>>>(xb, Wkt, kb, 512,   EMBED, NKV, 1.0f);
  gemm_bt<1><<<(MROWS/128)*(512/128),   256, 0, stream>>>(xb, Wvt, vb, 512,   EMBED, NKV, 1.0f);
  trans_v<<<4*64*BB*NKV, 256, 0, stream>>>(vb, vtb);

  attn_kernel<<<BB*NH*16, 256, 0, stream>>>(qb, kb, vtb, ob);

  gemm_bt<0><<<(MROWS/128)*(EMBED/128), 256, 0, stream>>>(ob, Wot, d_out, EMBED, EMBED, 0, 1.0f);
}

// Round 5
// 312.815 us; speedup vs baseline: 2.5017x; 1.2372x over previous
//
#include <hip/hip_runtime.h>

typedef unsigned short u16;
typedef unsigned int   u32;
typedef __attribute__((ext_vector_type(4))) float  f32x4;
typedef __attribute__((ext_vector_type(8))) __bf16 bf16x8;

#define EMBED 2048
#define NH    16
#define NKV   4
#define HD    128
#define TT    2048
#define BB    2
#define MROWS (BB*TT)
#define QSCALE 0.08838834764831845f

#define QELEMS ((size_t)BB*NH*TT*HD)
#define KELEMS ((size_t)BB*NKV*TT*HD)

static __device__ __forceinline__ u16 f2b(float f){
  union { float f; u32 u; } v; v.f = f;
  u32 u = v.u;
  u32 r = u + 0x7FFFu + ((u >> 16) & 1u);   // RNE
  return (u16)(r >> 16);
}

// ---------------- fp32 -> bf16 convert (x) ----------------
__global__ __launch_bounds__(256) void cvt_f32_bf16(const float* __restrict__ in,
                                                    u16* __restrict__ out, int n4){
  int i = blockIdx.x * 256 + threadIdx.x;
  if (i >= n4) return;
  float4 v = ((const float4*)in)[i];
  uint2 o;
  o.x = (u32)f2b(v.x) | ((u32)f2b(v.y) << 16);
  o.y = (u32)f2b(v.z) | ((u32)f2b(v.w) << 16);
  ((uint2*)out)[i] = o;
}

// ---------------- fp32 [R][C] -> bf16 [C][R], two matrices per launch (z-dim) ----------------
__global__ __launch_bounds__(256) void trans_w2(const float* __restrict__ in0, u16* __restrict__ out0,
                                                const float* __restrict__ in1, u16* __restrict__ out1,
                                                int R, int C){
  const float* in = blockIdx.z ? in1 : in0;
  u16*        out = blockIdx.z ? out1 : out0;
  __shared__ u16 tile[32][33];
  int c0 = blockIdx.x * 32, r0 = blockIdx.y * 32;
  int tx = threadIdx.x & 31, ty = threadIdx.x >> 5;   // 32 x 8
  #pragma unroll
  for (int j = 0; j < 32; j += 8)
    tile[ty + j][tx] = f2b(in[(size_t)(r0 + ty + j) * C + c0 + tx]);
  __syncthreads();
  #pragma unroll
  for (int j = 0; j < 32; j += 8)
    out[(size_t)(c0 + ty + j) * R + r0 + tx] = tile[tx][ty + j];
}

// ---------------- bf16 [BH][T][D] -> [BH][D][T]  (V for PV fragment reads) ----------------
__global__ __launch_bounds__(256) void trans_v(const u16* __restrict__ in,
                                               u16* __restrict__ out){
  __shared__ u16 tile[32][33];
  int d0 = (blockIdx.x & 3) * 32;            // D/32 = 4
  int t0 = ((blockIdx.x >> 2) & 63) * 32;    // T/32 = 64
  int bh = blockIdx.x >> 8;                  // B*NKV = 8
  const u16* ip = in  + (size_t)bh * TT * HD;
  u16*       op = out + (size_t)bh * TT * HD;
  int tx = threadIdx.x & 31, ty = threadIdx.x >> 5;
  #pragma unroll
  for (int j = 0; j < 32; j += 8)
    tile[ty + j][tx] = ip[(size_t)(t0 + ty + j) * HD + d0 + tx];
  __syncthreads();
  #pragma unroll
  for (int j = 0; j < 32; j += 8)
    op[(size_t)(d0 + ty + j) * TT + t0 + tx] = tile[tx][ty + j];
}

// ---------------- bf16 GEMM: C[M,N] = A[M,K] * Bt[N,K]^T ----------------
// EPI 0: fp32 [M][N] out.
// EPI 2: fused QKV split — outp is the contiguous qkv buffer; block column band
//        (128 wide) maps to exactly one head, so routing is block-uniform.
template<int EPI>
__global__ __launch_bounds__(256)
void gemm_bt(const u16* __restrict__ A, const u16* __restrict__ Bt,
             void* __restrict__ outp, int N, int K){
  __shared__ __align__(16) u16 As[2][128*32];
  __shared__ __align__(16) u16 Bs[2][128*32];
  int tid  = threadIdx.x;
  int lane = tid & 63, w = tid >> 6;
  int nwg = gridDim.x;
  int bid = blockIdx.x;
  bid = (bid & 7) * (nwg >> 3) + (bid >> 3);      // XCD swizzle (nwg % 8 == 0 always here)
  int nbn  = N >> 7;
  int brow = (bid / nbn) * 128;
  int bcol = (bid % nbn) * 128;

  auto stage = [&](int buf, int kt){
    #pragma unroll
    for (int j = 0; j < 2; ++j){
      int boff  = w * 2048 + j * 1024;            // byte offset into 8KB tile (wave-uniform)
      int chunk = (boff >> 4) + lane;             // this lane's 16B chunk id
      int row   = chunk >> 2;                     // 4 chunks per 64B row
      int cko   = chunk & 3;
      const u16* ga = A  + (size_t)(brow + row) * K + kt + cko * 8;
      const u16* gb = Bt + (size_t)(bcol + row) * K + kt + cko * 8;
      __builtin_amdgcn_global_load_lds((__attribute__((address_space(1))) void*)(void*)ga,
          (__attribute__((address_space(3))) void*)(void*)(&As[buf][boff >> 1]), 16, 0, 0);
      __builtin_amdgcn_global_load_lds((__attribute__((address_space(1))) void*)(void*)gb,
          (__attribute__((address_space(3))) void*)(void*)(&Bs[buf][boff >> 1]), 16, 0, 0);
    }
  };

  int lr = lane & 15, lg = lane >> 4, lk = lg * 8;
  int wr = (w >> 1) * 64, wc = (w & 1) * 64;

  f32x4 acc[4][4];
  #pragma unroll
  for (int m = 0; m < 4; ++m)
    #pragma unroll
    for (int n = 0; n < 4; ++n)
      #pragma unroll
      for (int r = 0; r < 4; ++r) acc[m][n][r] = 0.f;

  int NT = K >> 5;
  stage(0, 0);
  asm volatile("s_waitcnt vmcnt(0)" ::: "memory");
  __syncthreads();
  int cur = 0;
  for (int t = 0; t < NT; ++t){
    if (t + 1 < NT) stage(cur ^ 1, (t + 1) * 32);
    const u16* as = As[cur];
    const u16* bs = Bs[cur];
    bf16x8 af[4], bfv[4];
    #pragma unroll
    for (int m = 0; m < 4; ++m) af[m]  = *(const bf16x8*)(as + (wr + m*16 + lr)*32 + lk);
    #pragma unroll
    for (int n = 0; n < 4; ++n) bfv[n] = *(const bf16x8*)(bs + (wc + n*16 + lr)*32 + lk);
    #pragma unroll
    for (int m = 0; m < 4; ++m)
      #pragma unroll
      for (int n = 0; n < 4; ++n)
        acc[m][n] = __builtin_amdgcn_mfma_f32_16x16x32_bf16(af[m], bfv[n], acc[m][n], 0, 0, 0);
    asm volatile("s_waitcnt vmcnt(0)" ::: "memory");
    __syncthreads();
    cur ^= 1;
  }

  if (EPI == 0){
    float* o = (float*)outp;
    #pragma unroll
    for (int m = 0; m < 4; ++m)
      #pragma unroll
      for (int r = 0; r < 4; ++r){
        int rowg = brow + wr + m*16 + lg*4 + r;
        float* orow = o + (size_t)rowg * N + bcol + wc + lr;
        #pragma unroll
        for (int n = 0; n < 4; ++n) orow[n*16] = acc[m][n][r];
      }
  } else {
    // EPI 2: route this block's 128-wide column band to q / k / v
    u16* qb = (u16*)outp;
    u16* kb = qb + QELEMS;
    u16* vb = kb + KELEMS;
    int hb = bcol >> 7;                 // 0..23
    int b  = brow >> 11;
    u16* hp; float s;
    if (hb < 16)      { hp = qb + ((size_t)(b*NH  +  hb     )) * TT * HD; s = QSCALE; }
    else if (hb < 20) { hp = kb + ((size_t)(b*NKV + (hb-16))) * TT * HD; s = 1.0f; }
    else              { hp = vb + ((size_t)(b*NKV + (hb-20))) * TT * HD; s = 1.0f; }
    #pragma unroll
    for (int m = 0; m < 4; ++m)
      #pragma unroll
      for (int r = 0; r < 4; ++r){
        int t = (brow + wr + m*16 + lg*4 + r) & (TT - 1);
        #pragma unroll
        for (int n = 0; n < 4; ++n){
          int d = wc + n*16 + lr;
          hp[(size_t)t * HD + d] = f2b(acc[m][n][r] * s);
        }
      }
  }
}

// ---------------- flash attention: LDS-staged K/V (XOR-swizzled), paired q-tiles, defer-max ----------------
// q[B,NH,T,D] (pre-scaled), k[B,NKV,T,D], vt[B,NKV,D,T] -> ob[B,T,NH,D] bf16
__global__ __launch_bounds__(256)
void attn_kernel(const u16* __restrict__ qb, const u16* __restrict__ kb,
                 const u16* __restrict__ vtb, u16* __restrict__ ob){
  __shared__ __align__(16) u16 Ks[2][64*128];   // [kv 64][d 128], chunk-swizzled
  __shared__ __align__(16) u16 Vs[2][128*64];   // [d 128][kv 64], chunk-swizzled
  __shared__ __align__(16) u16 pl[4][16*88];    // per-wave P scratch, stride 88
  int tid = threadIdx.x, lane = tid & 63, w = tid >> 6;
  int nwg = gridDim.x;                          // 512
  int bid = blockIdx.x;
  bid = (bid & 7) * (nwg >> 3) + (bid >> 3);    // chunked XCD swizzle: one (b,hkv) group per XCD
  int pair = bid & 15;
  int h    = (bid >> 4) & 15;
  int b    = bid >> 8;
  int hkv  = h >> 2;                            // GROUP = 4, consecutive repeat
  int lr = lane & 15, lg = lane >> 4, lk = lg * 8;
  int sw = (lr & 7) << 3;                       // read-side XOR (elements)

  const u16* qbase = qb  + ((size_t)b * NH  + h  ) * TT * HD;
  const u16* kbase = kb  + ((size_t)b * NKV + hkv) * TT * HD;
  const u16* vbase = vtb + ((size_t)b * NKV + hkv) * HD * TT;

  auto stage = [&](int buf, int kt){
    #pragma unroll
    for (int i = 0; i < 4; ++i){
      int c  = i * 256 + tid;                   // 16B-chunk id (per-lane)
      int ub = (i * 256 + w * 64) * 8;          // wave-uniform LDS elem base
      int kr = c >> 4, kc = (c & 15) ^ (kr & 7);        // K: 16 chunks per 256B row
      const u16* gk = kbase + (size_t)(kt * 64 + kr) * HD + kc * 8;
      __builtin_amdgcn_global_load_lds((__attribute__((address_space(1))) void*)(void*)gk,
          (__attribute__((address_space(3))) void*)(void*)(&Ks[buf][ub]), 16, 0, 0);
      int vr = c >> 3, vc = (c & 7) ^ (vr & 7);         // V: 8 chunks per 128B row
      const u16* gv = vbase + (size_t)vr * TT + kt * 64 + vc * 8;
      __builtin_amdgcn_global_load_lds((__attribute__((address_space(1))) void*)(void*)gv,
          (__attribute__((address_space(3))) void*)(void*)(&Vs[buf][ub]), 16, 0, 0);
    }
  };

  __bf16* plw = (__bf16*)pl[w];

  for (int half = 0; half < 2; ++half){
    int qt = half ? (31 - pair) : pair;
    int q0 = qt * 64 + w * 16;

    bf16x8 aq[4];
    #pragma unroll
    for (int s = 0; s < 4; ++s)
      aq[s] = *(const bf16x8*)(qbase + (size_t)(q0 + lr) * HD + s*32 + lk);

    f32x4 o_acc[8];
    #pragma unroll
    for (int dt = 0; dt < 8; ++dt)
      #pragma unroll
      for (int r = 0; r < 4; ++r) o_acc[dt][r] = 0.f;
    float mrow[4], lrow[4];
    #pragma unroll
    for (int r = 0; r < 4; ++r){ mrow[r] = -1e30f; lrow[r] = 0.f; }

    stage(0, 0);
    asm volatile("s_waitcnt vmcnt(0)" ::: "memory");
    __syncthreads();
    int cur = 0;
    for (int kt = 0; kt <= qt; ++kt){
      if (kt < qt) stage(cur ^ 1, kt + 1);
      // ---- scores = Q K^T (16 x 64) from swizzled LDS ----
      const u16* ks = Ks[cur];
      f32x4 sc[4];
      #pragma unroll
      for (int c = 0; c < 4; ++c)
        #pragma unroll
        for (int r = 0; r < 4; ++r) sc[c][r] = 0.f;
      __builtin_amdgcn_s_setprio(1);
      #pragma unroll
      for (int c = 0; c < 4; ++c){
        const u16* kp = ks + (c*16 + lr) * 128;
        #pragma unroll
        for (int s = 0; s < 4; ++s){
          bf16x8 kf = *(const bf16x8*)(kp + (((s*32) + lk) ^ sw));
          sc[c] = __builtin_amdgcn_mfma_f32_16x16x32_bf16(aq[s], kf, sc[c], 0, 0, 0);
        }
      }
      __builtin_amdgcn_s_setprio(0);
      if (kt == qt){
        #pragma unroll
        for (int c = 0; c < 4; ++c){
          int kvg = kt*64 + c*16 + lr;
          #pragma unroll
          for (int r = 0; r < 4; ++r){
            int qg = q0 + lg*4 + r;             // C-layout row
            if (kvg > qg) sc[c][r] = -1e30f;
          }
        }
      }
      // ---- online softmax with defer-max (T13): skip rescale unless max grew >8 ----
      float tmv[4];
      #pragma unroll
      for (int r = 0; r < 4; ++r){
        float tm = fmaxf(fmaxf(sc[0][r], sc[1][r]), fmaxf(sc[2][r], sc[3][r]));
        tm = fmaxf(tm, __shfl_xor(tm, 1));
        tm = fmaxf(tm, __shfl_xor(tm, 2));
        tm = fmaxf(tm, __shfl_xor(tm, 4));
        tm = fmaxf(tm, __shfl_xor(tm, 8));
        tmv[r] = tm;
      }
      bool need = (tmv[0] > mrow[0] + 8.f) || (tmv[1] > mrow[1] + 8.f) ||
                  (tmv[2] > mrow[2] + 8.f) || (tmv[3] > mrow[3] + 8.f);
      if (__any(need ? 1 : 0)){
        #pragma unroll
        for (int r = 0; r < 4; ++r){
          float mnew  = fmaxf(mrow[r], tmv[r]);
          float alpha = __expf(mrow[r] - mnew);
          mrow[r] = mnew;
          lrow[r] *= alpha;
          #pragma unroll
          for (int dt = 0; dt < 8; ++dt) o_acc[dt][r] *= alpha;
        }
      }
      #pragma unroll
      for (int r = 0; r < 4; ++r){
        float rs = 0.f;
        #pragma unroll
        for (int c = 0; c < 4; ++c){
          float p = __expf(sc[c][r] - mrow[r]);
          rs += p;
          plw[(lg*4 + r)*88 + c*16 + lr] = (__bf16)p;
        }
        rs += __shfl_xor(rs, 1); rs += __shfl_xor(rs, 2);
        rs += __shfl_xor(rs, 4); rs += __shfl_xor(rs, 8);
        lrow[r] += rs;
      }
      asm volatile("s_waitcnt lgkmcnt(0)" ::: "memory");
      // ---- O += P V from swizzled LDS ----
      bf16x8 pa[2];
      #pragma unroll
      for (int kk = 0; kk < 2; ++kk)
        pa[kk] = *(const bf16x8*)((const u16*)plw + lr*88 + kk*32 + lk);
      const u16* vs = Vs[cur];
      __builtin_amdgcn_s_setprio(1);
      #pragma unroll
      for (int dt = 0; dt < 8; ++dt){
        const u16* vp = vs + (dt*16 + lr) * 64;
        #pragma unroll
        for (int kk = 0; kk < 2; ++kk){
          bf16x8 vf = *(const bf16x8*)(vp + (((kk*32) + lk) ^ sw));
          o_acc[dt] = __builtin_amdgcn_mfma_f32_16x16x32_bf16(pa[kk], vf, o_acc[dt], 0, 0, 0);
        }
      }
      __builtin_amdgcn_s_setprio(0);
      asm volatile("s_waitcnt vmcnt(0)" ::: "memory");
      __syncthreads();
      cur ^= 1;
    }
    // ---- epilogue: ob[b][t][h*128+d] = O / l ----
    #pragma unroll
    for (int r = 0; r < 4; ++r){
      float inv = 1.0f / lrow[r];
      int t = q0 + lg*4 + r;
      size_t base = ((size_t)b * TT + t) * EMBED + h * HD;
      #pragma unroll
      for (int dt = 0; dt < 8; ++dt)
        ob[base + dt*16 + lr] = f2b(o_acc[dt][r] * inv);
    }
  }
}

extern "C" void kernel_launch(void* const* d_in, const int* in_sizes, int n_in,
                              void* d_out, int out_size, void* d_ws, size_t ws_size,
                              hipStream_t stream){
  const float* x  = (const float*)d_in[0];
  const float* Wq = (const float*)d_in[1];
  const float* Wk = (const float*)d_in[2];
  const float* Wv = (const float*)d_in[3];
  const float* Wo = (const float*)d_in[4];

  char* ws = (char*)d_ws;
  size_t off = 0;
  auto alloc = [&](size_t bytes){ void* p = ws + off; off += (bytes + 255) & ~(size_t)255; return p; };
  u16* xb    = (u16*)alloc((size_t)MROWS * EMBED * 2);
  u16* Wqkvt = (u16*)alloc((size_t)3072 * EMBED * 2);        // rows: 0..2047 Wq, 2048..2559 Wk, 2560..3071 Wv
  u16* Wot   = (u16*)alloc((size_t)EMBED * EMBED * 2);
  u16* qkv   = (u16*)alloc((QELEMS + 2*KELEMS) * 2);          // q | k | v contiguous
  u16* vtb   = (u16*)alloc(KELEMS * 2);
  u16* ob    = (u16*)alloc((size_t)MROWS * EMBED * 2);

  u16* qb = qkv;
  u16* kb = qb + QELEMS;
  u16* vb = kb + KELEMS;

  cvt_f32_bf16<<<(MROWS*EMBED/4 + 255)/256, 256, 0, stream>>>(x, xb, MROWS*EMBED/4);
  trans_w2<<<dim3(EMBED/32, EMBED/32, 2), 256, 0, stream>>>(Wq, Wqkvt, Wo, Wot, EMBED, EMBED);
  trans_w2<<<dim3(512/32,   EMBED/32, 2), 256, 0, stream>>>(Wk, Wqkvt + (size_t)2048*EMBED,
                                                            Wv, Wqkvt + (size_t)2560*EMBED, EMBED, 512);

  gemm_bt<2><<<(MROWS/128)*(3072/128), 256, 0, stream>>>(xb, Wqkvt, qkv, 3072, EMBED);
  trans_v<<<4*64*BB*NKV, 256, 0, stream>>>(vb, vtb);

  attn_kernel<<<BB*NH*16, 256, 0, stream>>>(qb, kb, vtb, ob);

  gemm_bt<0><<<(MROWS/128)*(EMBED/128), 256, 0, stream>>>(ob, Wot, d_out, EMBED, EMBED);
}